// Round 2
// baseline (97.605 us; speedup 1.0000x reference)
//
#include <hip/hip_runtime.h>
#include <math.h>

#define S 2048
#define B 64
#define H 1024
#define SPW 8   // s-rows per wave

// Kernel 1: scores[b*S + s] = dot(hidden[b,:], enc[s,b,:]) over H.
// One 64-lane wave per (b, 8 consecutive s). hidden[b] is loaded into
// registers ONCE (4 float4/lane) and reused across the 8 encoder rows,
// halving vmem instruction count vs one-wave-per-(s,b).
// Each e-load: 64 lanes x 16B = 1 KiB contiguous (fully coalesced).
__global__ __launch_bounds__(256) void score_kernel(const float* __restrict__ hidden,
                                                    const float* __restrict__ enc,
                                                    float* __restrict__ scores) {
    const int w    = blockIdx.x * 4 + (threadIdx.x >> 6);  // global wave id
    const int lane = threadIdx.x & 63;
    const int b  = w & 63;        // w % B
    const int sg = w >> 6;        // s-group: rows sg*8 .. sg*8+7

    const float4* h4 = reinterpret_cast<const float4*>(hidden + (size_t)b * H);
    float4 h0 = h4[0 * 64 + lane];
    float4 h1 = h4[1 * 64 + lane];
    float4 h2 = h4[2 * 64 + lane];
    float4 h3 = h4[3 * 64 + lane];

    const float4* e4 = reinterpret_cast<const float4*>(
        enc + (size_t)(sg * SPW) * (B * H) + (size_t)b * H);
    const size_t row_stride4 = (size_t)B * H / 4;   // float4 stride between s

    float acc[SPW];
#pragma unroll
    for (int k = 0; k < SPW; ++k) {
        const float4* er = e4 + (size_t)k * row_stride4;
        float4 e0 = er[0 * 64 + lane];
        float4 e1 = er[1 * 64 + lane];
        float4 e2 = er[2 * 64 + lane];
        float4 e3 = er[3 * 64 + lane];
        float a = e0.x * h0.x + e0.y * h0.y + e0.z * h0.z + e0.w * h0.w;
        a += e1.x * h1.x + e1.y * h1.y + e1.z * h1.z + e1.w * h1.w;
        a += e2.x * h2.x + e2.y * h2.y + e2.z * h2.z + e2.w * h2.w;
        a += e3.x * h3.x + e3.y * h3.y + e3.z * h3.z + e3.w * h3.w;
        acc[k] = a;
    }

#pragma unroll
    for (int k = 0; k < SPW; ++k) {
#pragma unroll
        for (int off = 32; off; off >>= 1)
            acc[k] += __shfl_down(acc[k], off, 64);
    }
    if (lane == 0) {
        float* dst = scores + (size_t)b * S + sg * SPW;
#pragma unroll
        for (int k = 0; k < SPW; ++k)
            dst[k] = acc[k];
    }
}

// Kernel 2: per-b softmax over S=2048. One block of 256 threads per b.
__global__ __launch_bounds__(256) void softmax_kernel(const float* __restrict__ scores,
                                                      float* __restrict__ out) {
    const int b = blockIdx.x;
    const float* row  = scores + b * S;
    float*       orow = out    + b * S;   // out is [B,1,S] -> flat b*S+s
    const int tid  = threadIdx.x;
    const int wid  = tid >> 6;
    const int lane = tid & 63;

    float v[8];
    float m = -INFINITY;
#pragma unroll
    for (int k = 0; k < 8; ++k) {
        v[k] = row[tid + k * 256];
        m = fmaxf(m, v[k]);
    }
#pragma unroll
    for (int off = 32; off; off >>= 1)
        m = fmaxf(m, __shfl_xor(m, off, 64));

    __shared__ float redm[4];
    __shared__ float reds[4];
    if (lane == 0) redm[wid] = m;
    __syncthreads();
    m = fmaxf(fmaxf(redm[0], redm[1]), fmaxf(redm[2], redm[3]));

    float sum = 0.f;
#pragma unroll
    for (int k = 0; k < 8; ++k) {
        v[k] = __expf(v[k] - m);
        sum += v[k];
    }
#pragma unroll
    for (int off = 32; off; off >>= 1)
        sum += __shfl_xor(sum, off, 64);
    if (lane == 0) reds[wid] = sum;
    __syncthreads();
    sum = reds[0] + reds[1] + reds[2] + reds[3];

    const float inv = 1.f / sum;
#pragma unroll
    for (int k = 0; k < 8; ++k)
        orow[tid + k * 256] = v[k] * inv;
}

extern "C" void kernel_launch(void* const* d_in, const int* in_sizes, int n_in,
                              void* d_out, int out_size, void* d_ws, size_t ws_size,
                              hipStream_t stream) {
    const float* hidden = (const float*)d_in[0];   // [1,B,H]
    const float* enc    = (const float*)d_in[1];   // [S,B,H]
    float*       out    = (float*)d_out;           // [B,1,S]
    float*       scores = (float*)d_ws;            // B*S floats = 512 KiB

    const int nwaves = (S / SPW) * B;              // 16384
    score_kernel<<<nwaves / 4, 256, 0, stream>>>(hidden, enc, scores);
    softmax_kernel<<<B, 256, 0, stream>>>(scores, out);
}

// Round 3
// 96.279 us; speedup vs baseline: 1.0138x; 1.0138x over previous
//
#include <hip/hip_runtime.h>
#include <math.h>

#define S 2048
#define B 64
#define H 1024
#define NITER 16   // s-tasks per persistent wave

// Kernel 1: scores[b*S + s] = dot(hidden[b,:], enc[s,b,:]) over H.
// Persistent: 8192 waves (2048 blocks x 4). Wave v owns b = v%64, and
// iterates s = (v/64) + 128*i, i=0..15. hidden[b] stays in registers for
// all 16 tasks. At any instant the 8192 waves cover a contiguous
// [128-s x 64-b] = 32 MiB slab of enc that slides forward -> same
// streaming locality as one-wave-per-(s,b), but ~half the vmem instrs
// and no wave relaunch churn. ~50 VGPRs -> full occupancy.
__global__ __launch_bounds__(256) void score_kernel(const float* __restrict__ hidden,
                                                    const float* __restrict__ enc,
                                                    float* __restrict__ scores) {
    const int v    = blockIdx.x * 4 + (threadIdx.x >> 6);  // wave id [0,8192)
    const int lane = threadIdx.x & 63;
    const int b    = v & 63;
    const int s0   = v >> 6;                               // [0,128)

    const float4* h4 = reinterpret_cast<const float4*>(hidden + (size_t)b * H);
    const float4 h0 = h4[0 * 64 + lane];
    const float4 h1 = h4[1 * 64 + lane];
    const float4 h2 = h4[2 * 64 + lane];
    const float4 h3 = h4[3 * 64 + lane];

    const size_t row4 = (size_t)B * H / 4;                 // float4 per s-row
    float* srow = scores + (size_t)b * S;

    for (int i = 0; i < NITER; ++i) {
        const int s = s0 + 128 * i;
        const float4* er = reinterpret_cast<const float4*>(enc) + (size_t)s * row4 + (size_t)b * (H / 4);
        float4 e0 = er[0 * 64 + lane];
        float4 e1 = er[1 * 64 + lane];
        float4 e2 = er[2 * 64 + lane];
        float4 e3 = er[3 * 64 + lane];
        float a = e0.x * h0.x + e0.y * h0.y + e0.z * h0.z + e0.w * h0.w;
        a += e1.x * h1.x + e1.y * h1.y + e1.z * h1.z + e1.w * h1.w;
        a += e2.x * h2.x + e2.y * h2.y + e2.z * h2.z + e2.w * h2.w;
        a += e3.x * h3.x + e3.y * h3.y + e3.z * h3.z + e3.w * h3.w;
#pragma unroll
        for (int off = 32; off; off >>= 1)
            a += __shfl_down(a, off, 64);
        if (lane == 0)
            srow[s] = a;
    }
}

// Kernel 2: per-b softmax over S=2048. One block of 256 threads per b.
__global__ __launch_bounds__(256) void softmax_kernel(const float* __restrict__ scores,
                                                      float* __restrict__ out) {
    const int b = blockIdx.x;
    const float* row  = scores + b * S;
    float*       orow = out    + b * S;   // out is [B,1,S] -> flat b*S+s
    const int tid  = threadIdx.x;
    const int wid  = tid >> 6;
    const int lane = tid & 63;

    float v[8];
    float m = -INFINITY;
#pragma unroll
    for (int k = 0; k < 8; ++k) {
        v[k] = row[tid + k * 256];
        m = fmaxf(m, v[k]);
    }
#pragma unroll
    for (int off = 32; off; off >>= 1)
        m = fmaxf(m, __shfl_xor(m, off, 64));

    __shared__ float redm[4];
    __shared__ float reds[4];
    if (lane == 0) redm[wid] = m;
    __syncthreads();
    m = fmaxf(fmaxf(redm[0], redm[1]), fmaxf(redm[2], redm[3]));

    float sum = 0.f;
#pragma unroll
    for (int k = 0; k < 8; ++k) {
        v[k] = __expf(v[k] - m);
        sum += v[k];
    }
#pragma unroll
    for (int off = 32; off; off >>= 1)
        sum += __shfl_xor(sum, off, 64);
    if (lane == 0) reds[wid] = sum;
    __syncthreads();
    sum = reds[0] + reds[1] + reds[2] + reds[3];

    const float inv = 1.f / sum;
#pragma unroll
    for (int k = 0; k < 8; ++k)
        orow[tid + k * 256] = v[k] * inv;
}

extern "C" void kernel_launch(void* const* d_in, const int* in_sizes, int n_in,
                              void* d_out, int out_size, void* d_ws, size_t ws_size,
                              hipStream_t stream) {
    const float* hidden = (const float*)d_in[0];   // [1,B,H]
    const float* enc    = (const float*)d_in[1];   // [S,B,H]
    float*       out    = (float*)d_out;           // [B,1,S]
    float*       scores = (float*)d_ws;            // B*S floats = 512 KiB

    score_kernel<<<2048, 256, 0, stream>>>(hidden, enc, scores);
    softmax_kernel<<<B, 256, 0, stream>>>(scores, out);
}

// Round 5
// 85.954 us; speedup vs baseline: 1.1355x; 1.1201x over previous
//
#include <hip/hip_runtime.h>
#include <math.h>

#define S 2048
#define B 64
#define H 1024

typedef float f4 __attribute__((ext_vector_type(4)));   // clang vector: nt-load-able

// Kernel 1: scores[b*S + s] = dot(hidden[b,:], enc[s,b,:]) over H.
// One 64-lane wave per (s,b) — R1 structure (best measured: 89.8 us).
// Lane i reads float4 at k*256 + i*4 -> 1 KiB contiguous per instruction.
// enc is streamed once with nontemporal loads (no cache allocation);
// hidden stays cached (reused by 2048 waves per b).
__global__ __launch_bounds__(256) void score_kernel(const float* __restrict__ hidden,
                                                    const float* __restrict__ enc,
                                                    float* __restrict__ scores) {
    const int w    = blockIdx.x * 4 + (threadIdx.x >> 6);  // global wave id
    const int lane = threadIdx.x & 63;
    const int s = w >> 6;   // w / B   (B == 64)
    const int b = w & 63;   // w % B
    const f4* e4 = reinterpret_cast<const f4*>(enc + (size_t)s * (B * H) + (size_t)b * H);
    const f4* h4 = reinterpret_cast<const f4*>(hidden + (size_t)b * H);
    float acc = 0.f;
#pragma unroll
    for (int k = 0; k < 4; ++k) {          // H/4 = 256 float4 per row / 64 lanes = 4
        f4 e = __builtin_nontemporal_load(&e4[k * 64 + lane]);
        f4 h = h4[k * 64 + lane];
        acc += e.x * h.x + e.y * h.y + e.z * h.z + e.w * h.w;
    }
#pragma unroll
    for (int off = 32; off; off >>= 1)
        acc += __shfl_down(acc, off, 64);
    if (lane == 0)
        scores[b * S + s] = acc;
}

// Kernel 2: per-b softmax over S=2048. One block of 256 threads per b.
__global__ __launch_bounds__(256) void softmax_kernel(const float* __restrict__ scores,
                                                      float* __restrict__ out) {
    const int b = blockIdx.x;
    const float* row  = scores + b * S;
    float*       orow = out    + b * S;   // out is [B,1,S] -> flat b*S+s
    const int tid  = threadIdx.x;
    const int wid  = tid >> 6;
    const int lane = tid & 63;

    float v[8];
    float m = -INFINITY;
#pragma unroll
    for (int k = 0; k < 8; ++k) {
        v[k] = row[tid + k * 256];
        m = fmaxf(m, v[k]);
    }
#pragma unroll
    for (int off = 32; off; off >>= 1)
        m = fmaxf(m, __shfl_xor(m, off, 64));

    __shared__ float redm[4];
    __shared__ float reds[4];
    if (lane == 0) redm[wid] = m;
    __syncthreads();
    m = fmaxf(fmaxf(redm[0], redm[1]), fmaxf(redm[2], redm[3]));

    float sum = 0.f;
#pragma unroll
    for (int k = 0; k < 8; ++k) {
        v[k] = __expf(v[k] - m);
        sum += v[k];
    }
#pragma unroll
    for (int off = 32; off; off >>= 1)
        sum += __shfl_xor(sum, off, 64);
    if (lane == 0) reds[wid] = sum;
    __syncthreads();
    sum = reds[0] + reds[1] + reds[2] + reds[3];

    const float inv = 1.f / sum;
#pragma unroll
    for (int k = 0; k < 8; ++k)
        orow[tid + k * 256] = v[k] * inv;
}

extern "C" void kernel_launch(void* const* d_in, const int* in_sizes, int n_in,
                              void* d_out, int out_size, void* d_ws, size_t ws_size,
                              hipStream_t stream) {
    const float* hidden = (const float*)d_in[0];   // [1,B,H]
    const float* enc    = (const float*)d_in[1];   // [S,B,H]
    float*       out    = (float*)d_out;           // [B,1,S]
    float*       scores = (float*)d_ws;            // B*S floats = 512 KiB

    score_kernel<<<(S * B) / 4, 256, 0, stream>>>(hidden, enc, scores);
    softmax_kernel<<<B, 256, 0, stream>>>(scores, out);
}